// Round 6
// baseline (166.048 us; speedup 1.0000x reference)
//
#include <hip/hip_runtime.h>
#include <hip/hip_fp16.h>

// N = 40000 nodes, E = 640000 edges, F = 128 features, K = 2 hops.
// Floors: fills ~89us (harness, fixed); prep ~9us (BW, 48.6MB); finalize
// ~5us; hops ~24/25.5us. R5 fusion landed (-8.5us, predicted).
// THIS ROUND: degree-balanced wave pairing. Hops' loop bound is
// max(c_A,c_B) over the wave's node pair: E[max of 2 Poi(16)] ~ 18.3 vs
// mean 16.1 -> ~13% padded iterations. finalize now emits a per-bin
// degree-sorted permutation (65-bin LDS counting sort, ~free); hops
// process perm[gid] so paired nodes have near-equal degree. Bucket order
// per node unchanged -> bit-identical numerics (absmax stays 0.0078125).
// Predicted: hop1 24->~21, hop_linear 25.5->~22.5, total ~159 -> ~154.
// Pre-committed: if hops unchanged, iteration count isn't the limiter ->
// request-rate floor confirmed from a 5th angle -> declare roofline.

#define F    128
#define CAP  64
#define EPB  4096   // edges per build block
#define BPT  16     // EPB / 256
#define TPAD 136    // LDS tile row stride (fp16) - bank spread

typedef _Float16 f16x8 __attribute__((ext_vector_type(8)));
typedef float    f32x4 __attribute__((ext_vector_type(4)));

// ---------------------------------------------------------------------------
// K1: build-partition (LDS atomics only) + x fp32->fp16 + W fp32->fp16.
// coarse entry: .x = r | (half(w)<<16)  (final bucket format), .y = c & 0xFF.
// Assumes nbin <= 256 and nb1 <= 256 (true for N=40000, E=640000).
__global__ __launch_bounds__(256) void prep_kernel(
    const float2* __restrict__ x2in, __half2* __restrict__ xh, int npairs,
    const int* __restrict__ ei, const float* __restrict__ ew,
    uint2* __restrict__ coarse, int* __restrict__ cnt1, int E,
    int nbin, int nb1,
    const float2* __restrict__ W2, __half2* __restrict__ Wh2,
    int buildBlocks, int cvtBlocks) {
    int b = blockIdx.x;
    if (b < buildBlocks) {
        __shared__ int binCnt[256];
        int t = threadIdx.x;
        if (t < nbin) binCnt[t] = 0;
        __syncthreads();
        int base = b * EPB;
        // Phase 1: batch-load 16 edges/thread (one latency, 48 loads in flight)
        unsigned rc[BPT]; unsigned short hw[BPT];
        #pragma unroll
        for (int j = 0; j < BPT; ++j) {
            int e = base + j * 256 + t;
            bool v = e < E;
            int   r = v ? ei[e]     : 0;
            int   c = v ? ei[E + e] : 0;
            float w = v ? ew[e]     : 0.f;
            rc[j] = v ? ((unsigned)r | ((unsigned)c << 16)) : 0xFFFFFFFFu;
            hw[j] = __half_as_ushort(__float2half(w));
        }
        // Phase 2: LDS-atomic rank -> private segment store (fire-and-forget)
        #pragma unroll
        for (int j = 0; j < BPT; ++j) {
            if (rc[j] == 0xFFFFFFFFu) continue;   // r,c < 40000 -> never all-ones
            int c   = (int)(rc[j] >> 16);
            int bin = c >> 8;
            int rank = atomicAdd(&binCnt[bin], 1);
            if (rank < CAP) {
                uint2 ent;
                ent.x = (rc[j] & 0xFFFFu) | ((unsigned)hw[j] << 16);
                ent.y = (unsigned)(c & 0xFF);
                coarse[((size_t)bin * nb1 + b) * CAP + rank] = ent;
            }
        }
        __syncthreads();
        if (t < nbin) cnt1[(size_t)b * nbin + t] = min(binCnt[t], CAP);
    } else if (b < buildBlocks + cvtBlocks) {
        int idx = (b - buildBlocks) * 256 + threadIdx.x;  // over N*64 pairs
        if (idx < npairs) xh[idx] = __float22half2_rn(x2in[idx]);
    } else {
        int idx = (b - buildBlocks - cvtBlocks) * 256 + threadIdx.x;
        if (idx < F * F / 2) Wh2[idx] = __float22half2_rn(W2[idx]);
    }
}

// ---------------------------------------------------------------------------
// K2: finalize. One block of 1024 threads (16 waves) per bin (256 nodes).
// Gathers the bin's nb1 segments, LDS-atomic final slot per node, writes
// bucket + cnt + dinv. NEW: emits per-bin degree-sorted permutation via a
// 65-bin LDS counting sort (hops pair perm-adjacent nodes -> equal degree).
__global__ __launch_bounds__(1024) void finalize_kernel(
    const uint2* __restrict__ coarse, const int* __restrict__ cnt1,
    unsigned int* __restrict__ bucket, int* __restrict__ cnt,
    float* __restrict__ dinv, int* __restrict__ perm,
    int N, int nbin, int nb1) {
    __shared__ int   nodeCnt[256];
    __shared__ float degS[256];
    __shared__ int   c1s[256];
    __shared__ int   hoff[CAP + 1];
    int b = blockIdx.x;
    int t = threadIdx.x;
    if (t < 256) {
        nodeCnt[t] = 0;
        degS[t]    = 0.f;
    }
    if (t >= 256 && t < 256 + CAP + 1) hoff[t - 256] = 0;
    for (int i = t; i < nb1; i += 1024) c1s[i] = cnt1[(size_t)i * nbin + b];
    __syncthreads();
    int tot = nb1 * CAP;
    for (int s = t; s < tot; s += 1024) {
        int blk = s >> 6, slot = s & 63;
        if (slot < c1s[blk]) {
            uint2 ent = coarse[((size_t)b * nb1 + blk) * CAP + slot];
            int local = (int)(ent.y & 0xFFu);
            int rank  = atomicAdd(&nodeCnt[local], 1);
            float wf  = __half2float(__ushort_as_half((unsigned short)(ent.x >> 16)));
            atomicAdd(&degS[local], wf);   // LDS float add (ds_add_f32)
            if (rank < CAP)
                bucket[(((size_t)b << 8) | (unsigned)local) * CAP + rank] = ent.x;
        }
    }
    __syncthreads();
    int node = (b << 8) + t;
    int myDeg = 0;
    if (t < 256 && node < N) {
        myDeg = min(nodeCnt[t], CAP);
        cnt[node]  = myDeg;
        dinv[node] = 1.0f / sqrtf(degS[t] + 1.0f);
        atomicAdd(&hoff[myDeg], 1);          // degree histogram
    }
    __syncthreads();
    if (t == 0) {                            // exclusive scan, 65 bins
        int run = 0;
        #pragma unroll
        for (int j = 0; j <= CAP; ++j) { int c = hoff[j]; hoff[j] = run; run += c; }
    }
    __syncthreads();
    if (t < 256 && node < N) {
        int rank = atomicAdd(&hoff[myDeg], 1);
        perm[(b << 8) + rank] = node;        // bin-local bijection
    }
}

// ---------------------------------------------------------------------------
// K3: hop 1, fp16 -> fp16, full-row [N][128]. Half-wave (32 lanes) per
// node, lane = 4 feats (8B) -> one dwordx2 = 512B/wave (2 edges). 8x unroll.
// Nodes taken via degree-sorted perm -> wave's pair has near-equal degree.
__global__ __launch_bounds__(256) void hop_kernel(
    const unsigned short* __restrict__ xin, unsigned short* __restrict__ xout,
    const float* __restrict__ dinv, const unsigned int* __restrict__ bucket,
    const int* __restrict__ cnt, const int* __restrict__ perm) {
    int t = threadIdx.x;
    int lane = t & 63;
    int wid  = t >> 6;
    int q = lane & 31;                       // lane within half-wave
    int h = lane >> 5;                       // which half
    int gid = blockIdx.x * 8 + wid * 2 + h;
    int i = perm[gid];                       // node for this half-wave

    int c = min(cnt[i], CAP);
    float di = dinv[i];
    int r0 = i, r1 = i;
    float n0 = 0.0f, n1 = 0.0f;
    if (q < c) {
        unsigned int ent = bucket[i * CAP + q];
        r0 = (int)(ent & 0xFFFFu);
        float w = __half2float(__ushort_as_half((unsigned short)(ent >> 16)));
        n0 = di * dinv[r0] * w;
    }
    if (q + 32 < c) {
        unsigned int ent = bucket[i * CAP + q + 32];
        r1 = (int)(ent & 0xFFFFu);
        float w = __half2float(__ushort_as_half((unsigned short)(ent >> 16)));
        n1 = di * dinv[r1] * w;
    }
    int cmax = max(c, __shfl_xor(c, 32, 64));   // wave-uniform loop bound

    uint2 sv = *(const uint2*)(xin + (size_t)i * F + q * 4);
    float2 slo = __half22float2(*(const __half2*)&sv.x);
    float2 shi = __half22float2(*(const __half2*)&sv.y);
    float dii = di * di;
    float4 acc = make_float4(dii * slo.x, dii * slo.y, dii * shi.x, dii * shi.y);

    int kend1 = cmax < 32 ? cmax : 32;
    int k = 0;
    for (; k + 8 <= kend1; k += 8) {
        int rr[8]; float nn[8]; uint2 v[8];
        #pragma unroll
        for (int j = 0; j < 8; ++j) {
            rr[j] = __shfl(r0, k + j, 32);
            nn[j] = __shfl(n0, k + j, 32);
        }
        #pragma unroll
        for (int j = 0; j < 8; ++j)
            v[j] = *(const uint2*)(xin + (size_t)rr[j] * F + q * 4);
        #pragma unroll
        for (int j = 0; j < 8; ++j) {
            float2 lo = __half22float2(*(const __half2*)&v[j].x);
            float2 hi = __half22float2(*(const __half2*)&v[j].y);
            acc.x += nn[j] * lo.x; acc.y += nn[j] * lo.y;
            acc.z += nn[j] * hi.x; acc.w += nn[j] * hi.y;
        }
    }
    for (; k < kend1; ++k) {
        int   rk = __shfl(r0, k, 32);
        float nk = __shfl(n0, k, 32);
        uint2 v  = *(const uint2*)(xin + (size_t)rk * F + q * 4);
        float2 lo = __half22float2(*(const __half2*)&v.x);
        float2 hi = __half22float2(*(const __half2*)&v.y);
        acc.x += nk * lo.x; acc.y += nk * lo.y;
        acc.z += nk * hi.x; acc.w += nk * hi.y;
    }
    for (; k + 8 <= cmax; k += 8) {
        int rr[8]; float nn[8]; uint2 v[8];
        #pragma unroll
        for (int j = 0; j < 8; ++j) {
            rr[j] = __shfl(r1, k - 32 + j, 32);
            nn[j] = __shfl(n1, k - 32 + j, 32);
        }
        #pragma unroll
        for (int j = 0; j < 8; ++j)
            v[j] = *(const uint2*)(xin + (size_t)rr[j] * F + q * 4);
        #pragma unroll
        for (int j = 0; j < 8; ++j) {
            float2 lo = __half22float2(*(const __half2*)&v[j].x);
            float2 hi = __half22float2(*(const __half2*)&v[j].y);
            acc.x += nn[j] * lo.x; acc.y += nn[j] * lo.y;
            acc.z += nn[j] * hi.x; acc.w += nn[j] * hi.y;
        }
    }
    for (; k < cmax; ++k) {
        int   rk = __shfl(r1, k - 32, 32);
        float nk = __shfl(n1, k - 32, 32);
        uint2 v  = *(const uint2*)(xin + (size_t)rk * F + q * 4);
        float2 lo = __half22float2(*(const __half2*)&v.x);
        float2 hi = __half22float2(*(const __half2*)&v.y);
        acc.x += nk * lo.x; acc.y += nk * lo.y;
        acc.z += nk * hi.x; acc.w += nk * hi.y;
    }

    uint2 o;
    *(__half2*)&o.x = __float22half2_rn(make_float2(acc.x, acc.y));
    *(__half2*)&o.y = __float22half2_rn(make_float2(acc.z, acc.w));
    *(uint2*)&xout[(size_t)i * F + q * 4] = o;
}

// ---------------------------------------------------------------------------
// K4: hop 2 fused with linear. 512 threads = 8 waves = 16 nodes/block.
// Gather loop identical to hop_kernel (nodes via perm); result staged as
// fp16 into LDS tile [16][TPAD], then wave `wid` computes out features
// [wid*16, wid*16+16) via 4 chained mfma_f32_16x16x32_f16 and writes `out`
// (+bias) directly. Tile row r <-> gid n0b+r <-> node perm[n0b+r].
__global__ __launch_bounds__(512) void hop_linear_kernel(
    const unsigned short* __restrict__ xin, const unsigned short* __restrict__ Wh,
    const float* __restrict__ bias, float* __restrict__ out,
    const float* __restrict__ dinv, const unsigned int* __restrict__ bucket,
    const int* __restrict__ cnt, const int* __restrict__ perm) {
    __shared__ unsigned short tile[16][TPAD];
    int t = threadIdx.x;
    int lane = t & 63;
    int wid  = t >> 6;                        // 0..7
    int q = lane & 31;                        // lane within half-wave
    int h = lane >> 5;                        // which half
    int row = wid * 2 + h;                    // tile row 0..15
    int n0b = blockIdx.x * 16;
    int i = perm[n0b + row];                  // node for this half-wave

    int c = min(cnt[i], CAP);
    float di = dinv[i];
    int r0 = i, r1 = i;
    float n0 = 0.0f, n1 = 0.0f;
    if (q < c) {
        unsigned int ent = bucket[i * CAP + q];
        r0 = (int)(ent & 0xFFFFu);
        float w = __half2float(__ushort_as_half((unsigned short)(ent >> 16)));
        n0 = di * dinv[r0] * w;
    }
    if (q + 32 < c) {
        unsigned int ent = bucket[i * CAP + q + 32];
        r1 = (int)(ent & 0xFFFFu);
        float w = __half2float(__ushort_as_half((unsigned short)(ent >> 16)));
        n1 = di * dinv[r1] * w;
    }
    int cmax = max(c, __shfl_xor(c, 32, 64));   // wave-uniform loop bound

    uint2 sv = *(const uint2*)(xin + (size_t)i * F + q * 4);
    float2 slo = __half22float2(*(const __half2*)&sv.x);
    float2 shi = __half22float2(*(const __half2*)&sv.y);
    float dii = di * di;
    float4 acc = make_float4(dii * slo.x, dii * slo.y, dii * shi.x, dii * shi.y);

    int kend1 = cmax < 32 ? cmax : 32;
    int k = 0;
    for (; k + 8 <= kend1; k += 8) {
        int rr[8]; float nn[8]; uint2 v[8];
        #pragma unroll
        for (int j = 0; j < 8; ++j) {
            rr[j] = __shfl(r0, k + j, 32);
            nn[j] = __shfl(n0, k + j, 32);
        }
        #pragma unroll
        for (int j = 0; j < 8; ++j)
            v[j] = *(const uint2*)(xin + (size_t)rr[j] * F + q * 4);
        #pragma unroll
        for (int j = 0; j < 8; ++j) {
            float2 lo = __half22float2(*(const __half2*)&v[j].x);
            float2 hi = __half22float2(*(const __half2*)&v[j].y);
            acc.x += nn[j] * lo.x; acc.y += nn[j] * lo.y;
            acc.z += nn[j] * hi.x; acc.w += nn[j] * hi.y;
        }
    }
    for (; k < kend1; ++k) {
        int   rk = __shfl(r0, k, 32);
        float nk = __shfl(n0, k, 32);
        uint2 v  = *(const uint2*)(xin + (size_t)rk * F + q * 4);
        float2 lo = __half22float2(*(const __half2*)&v.x);
        float2 hi = __half22float2(*(const __half2*)&v.y);
        acc.x += nk * lo.x; acc.y += nk * lo.y;
        acc.z += nk * hi.x; acc.w += nk * hi.y;
    }
    for (; k + 8 <= cmax; k += 8) {
        int rr[8]; float nn[8]; uint2 v[8];
        #pragma unroll
        for (int j = 0; j < 8; ++j) {
            rr[j] = __shfl(r1, k - 32 + j, 32);
            nn[j] = __shfl(n1, k - 32 + j, 32);
        }
        #pragma unroll
        for (int j = 0; j < 8; ++j)
            v[j] = *(const uint2*)(xin + (size_t)rr[j] * F + q * 4);
        #pragma unroll
        for (int j = 0; j < 8; ++j) {
            float2 lo = __half22float2(*(const __half2*)&v[j].x);
            float2 hi = __half22float2(*(const __half2*)&v[j].y);
            acc.x += nn[j] * lo.x; acc.y += nn[j] * lo.y;
            acc.z += nn[j] * hi.x; acc.w += nn[j] * hi.y;
        }
    }
    for (; k < cmax; ++k) {
        int   rk = __shfl(r1, k - 32, 32);
        float nk = __shfl(n1, k - 32, 32);
        uint2 v  = *(const uint2*)(xin + (size_t)rk * F + q * 4);
        float2 lo = __half22float2(*(const __half2*)&v.x);
        float2 hi = __half22float2(*(const __half2*)&v.y);
        acc.x += nk * lo.x; acc.y += nk * lo.y;
        acc.z += nk * hi.x; acc.w += nk * hi.y;
    }

    // stage fp16 row into LDS (same rounding as the old x2h path)
    uint2 o;
    *(__half2*)&o.x = __float22half2_rn(make_float2(acc.x, acc.y));
    *(__half2*)&o.y = __float22half2_rn(make_float2(acc.z, acc.w));
    *(uint2*)&tile[row][q * 4] = o;
    __syncthreads();

    // MFMA epilogue: wave wid -> out-features [wid*16, wid*16+16)
    int m    = lane & 15;
    int quad = lane >> 4;
    f32x4 acc2 = (f32x4){0.f, 0.f, 0.f, 0.f};
    #pragma unroll
    for (int ks = 0; ks < 4; ++ks) {
        f16x8 a = *(const f16x8*)&tile[m][ks * 32 + quad * 8];
        f16x8 b = *(const f16x8*)(Wh + (size_t)(wid * 16 + m) * F + ks * 32 + quad * 8);
        acc2 = __builtin_amdgcn_mfma_f32_16x16x32_f16(a, b, acc2, 0, 0, 0);
    }
    int f = wid * 16 + m;
    float bv = bias[f];
    #pragma unroll
    for (int reg = 0; reg < 4; ++reg) {
        int n = perm[n0b + quad * 4 + reg];   // true node id of tile row
        out[(size_t)n * F + f] = acc2[reg] + bv;
    }
}

// ---------------------------------------------------------------------------
extern "C" void kernel_launch(void* const* d_in, const int* in_sizes, int n_in,
                              void* d_out, int out_size, void* d_ws, size_t ws_size,
                              hipStream_t stream) {
    const float* x    = (const float*)d_in[0];
    const int*   ei   = (const int*)d_in[1];     // int32 per harness contract
    const float* ew   = (const float*)d_in[2];
    const float* W    = (const float*)d_in[3];
    const float* bias = (const float*)d_in[4];
    float* out = (float*)d_out;

    const int N = in_sizes[0] / F;   // 40000
    const int E = in_sizes[2];       // 640000

    const int nbin = (N + 255) >> 8;          // 157 bins of 256 nodes
    const int nb1  = (E + EPB - 1) / EPB;     // 157 build blocks

    // workspace layout (256B aligned); nothing needs zeroing
    char* ws = (char*)d_ws;
    size_t off = 0;
    auto take = [&](size_t bytes) {
        size_t r = off;
        off = (off + bytes + 255) & ~(size_t)255;
        return r;
    };
    size_t o_cnt1   = take((size_t)nb1 * nbin * 4);          // [blk][bin] counts
    size_t o_coarse = take((size_t)nbin * nb1 * CAP * 8);    // uint2 segments, 12.6MB
    size_t o_cnt    = take((size_t)N * 4);                   // int per node
    size_t o_dinv   = take((size_t)N * 4);                   // float
    size_t o_perm   = take((size_t)N * 4);                   // degree-sorted perm
    size_t o_bucket = take((size_t)N * CAP * 4);             // packed uint entries
    size_t o_xh     = take((size_t)N * F * 2);               // half [N][128]
    size_t o_x1h    = take((size_t)N * F * 2);               // half [N][128]
    size_t o_wh     = take((size_t)F * F * 2);               // half [128][128]
    (void)ws_size;

    int*            cnt1   = (int*)(ws + o_cnt1);
    uint2*          coarse = (uint2*)(ws + o_coarse);
    int*            cnt    = (int*)(ws + o_cnt);
    float*          dinv   = (float*)(ws + o_dinv);
    int*            perm   = (int*)(ws + o_perm);
    unsigned int*   bucket = (unsigned int*)(ws + o_bucket);
    __half2*        xh2    = (__half2*)(ws + o_xh);
    unsigned short* xh     = (unsigned short*)(ws + o_xh);
    unsigned short* x1h    = (unsigned short*)(ws + o_x1h);
    __half2*        wh2    = (__half2*)(ws + o_wh);
    unsigned short* wh     = (unsigned short*)(ws + o_wh);

    int npairs = N * 64;
    int cvtBlocks = (npairs + 255) / 256;      // 10000
    int wBlocks   = (F * F / 2 + 255) / 256;   // 32
    prep_kernel<<<nb1 + cvtBlocks + wBlocks, 256, 0, stream>>>(
        (const float2*)x, xh2, npairs, ei, ew, coarse, cnt1, E, nbin, nb1,
        (const float2*)W, wh2, nb1, cvtBlocks);
    finalize_kernel<<<nbin, 1024, 0, stream>>>(coarse, cnt1, bucket, cnt, dinv,
                                               perm, N, nbin, nb1);
    hop_kernel<<<N / 8, 256, 0, stream>>>(xh, x1h, dinv, bucket, cnt, perm);
    hop_linear_kernel<<<N / 16, 512, 0, stream>>>(x1h, wh, bias, out,
                                                  dinv, bucket, cnt, perm);
}

// Round 7
// 157.977 us; speedup vs baseline: 1.0511x; 1.0511x over previous
//
#include <hip/hip_runtime.h>
#include <hip/hip_fp16.h>

// N = 40000 nodes, E = 640000 edges, F = 128 features, K = 2 hops.
// FINAL STRUCTURE (R5, 159.3us measured):
//   fills ~89us  - harness poison of full 256MiB workspace, fixed.
//   prep  ~9us   - BW floor (48MB: x cvt 30MB, edges 8MB, coarse 10MB).
//   finalize ~5us- 1024-thr latency-hidden LDS counting sort.
//   hop1 ~24us, hop_linear ~25.5us - random-gather request-rate floor,
//     proven from 5 angles: 3 issue organizations, R4 source-sort (null),
//     R6 degree-balanced perm pairing (net NEGATIVE: indirection scatter
//     costs more than the 13% iteration saving).
//   linear fused into hop2 (R5, -8.5us).
// R6 post-mortem: perm pairing reverted. Any indirection added to the
// hops costs more than it saves; regular block-sequential row access is
// itself a load-bearing property.

#define F    128
#define CAP  64
#define EPB  4096   // edges per build block
#define BPT  16     // EPB / 256
#define TPAD 136    // LDS tile row stride (fp16) - bank spread

typedef _Float16 f16x8 __attribute__((ext_vector_type(8)));
typedef float    f32x4 __attribute__((ext_vector_type(4)));

// ---------------------------------------------------------------------------
// K1: build-partition (LDS atomics only) + x fp32->fp16 + W fp32->fp16.
// coarse entry: .x = r | (half(w)<<16)  (final bucket format), .y = c & 0xFF.
// Assumes nbin <= 256 and nb1 <= 256 (true for N=40000, E=640000).
__global__ __launch_bounds__(256) void prep_kernel(
    const float2* __restrict__ x2in, __half2* __restrict__ xh, int npairs,
    const int* __restrict__ ei, const float* __restrict__ ew,
    uint2* __restrict__ coarse, int* __restrict__ cnt1, int E,
    int nbin, int nb1,
    const float2* __restrict__ W2, __half2* __restrict__ Wh2,
    int buildBlocks, int cvtBlocks) {
    int b = blockIdx.x;
    if (b < buildBlocks) {
        __shared__ int binCnt[256];
        int t = threadIdx.x;
        if (t < nbin) binCnt[t] = 0;
        __syncthreads();
        int base = b * EPB;
        // Phase 1: batch-load 16 edges/thread (one latency, 48 loads in flight)
        unsigned rc[BPT]; unsigned short hw[BPT];
        #pragma unroll
        for (int j = 0; j < BPT; ++j) {
            int e = base + j * 256 + t;
            bool v = e < E;
            int   r = v ? ei[e]     : 0;
            int   c = v ? ei[E + e] : 0;
            float w = v ? ew[e]     : 0.f;
            rc[j] = v ? ((unsigned)r | ((unsigned)c << 16)) : 0xFFFFFFFFu;
            hw[j] = __half_as_ushort(__float2half(w));
        }
        // Phase 2: LDS-atomic rank -> private segment store (fire-and-forget)
        #pragma unroll
        for (int j = 0; j < BPT; ++j) {
            if (rc[j] == 0xFFFFFFFFu) continue;   // r,c < 40000 -> never all-ones
            int c   = (int)(rc[j] >> 16);
            int bin = c >> 8;
            int rank = atomicAdd(&binCnt[bin], 1);
            if (rank < CAP) {
                uint2 ent;
                ent.x = (rc[j] & 0xFFFFu) | ((unsigned)hw[j] << 16);
                ent.y = (unsigned)(c & 0xFF);
                coarse[((size_t)bin * nb1 + b) * CAP + rank] = ent;
            }
        }
        __syncthreads();
        if (t < nbin) cnt1[(size_t)b * nbin + t] = min(binCnt[t], CAP);
    } else if (b < buildBlocks + cvtBlocks) {
        int idx = (b - buildBlocks) * 256 + threadIdx.x;  // over N*64 pairs
        if (idx < npairs) xh[idx] = __float22half2_rn(x2in[idx]);
    } else {
        int idx = (b - buildBlocks - cvtBlocks) * 256 + threadIdx.x;
        if (idx < F * F / 2) Wh2[idx] = __float22half2_rn(W2[idx]);
    }
}

// ---------------------------------------------------------------------------
// K2: finalize (R3 proven version). One block of 1024 threads (16 waves)
// per bin (256 nodes). Gathers the bin's nb1 segments, LDS-atomic final
// slot per node, writes bucket + cnt + dinv.
__global__ __launch_bounds__(1024) void finalize_kernel(
    const uint2* __restrict__ coarse, const int* __restrict__ cnt1,
    unsigned int* __restrict__ bucket, int* __restrict__ cnt,
    float* __restrict__ dinv, int N, int nbin, int nb1) {
    __shared__ int   nodeCnt[256];
    __shared__ float degS[256];
    __shared__ int   c1s[256];
    int b = blockIdx.x;
    int t = threadIdx.x;
    if (t < 256) {
        nodeCnt[t] = 0;
        degS[t]    = 0.f;
    }
    for (int i = t; i < nb1; i += 1024) c1s[i] = cnt1[(size_t)i * nbin + b];
    __syncthreads();
    int tot = nb1 * CAP;
    for (int s = t; s < tot; s += 1024) {
        int blk = s >> 6, slot = s & 63;
        if (slot < c1s[blk]) {
            uint2 ent = coarse[((size_t)b * nb1 + blk) * CAP + slot];
            int local = (int)(ent.y & 0xFFu);
            int rank  = atomicAdd(&nodeCnt[local], 1);
            float wf  = __half2float(__ushort_as_half((unsigned short)(ent.x >> 16)));
            atomicAdd(&degS[local], wf);   // LDS float add (ds_add_f32)
            if (rank < CAP)
                bucket[(((size_t)b << 8) | (unsigned)local) * CAP + rank] = ent.x;
        }
    }
    __syncthreads();
    int node = (b << 8) + t;
    if (t < 256 && node < N) {
        cnt[node]  = min(nodeCnt[t], CAP);
        dinv[node] = 1.0f / sqrtf(degS[t] + 1.0f);
    }
}

// ---------------------------------------------------------------------------
// K3: hop 1, fp16 -> fp16, full-row [N][128]. Half-wave (32 lanes) per
// node, lane = 4 feats (8B) -> one dwordx2 = 512B/wave (2 edges). 8x unroll.
// (round-2 proven structure; block-sequential node order is load-bearing)
__global__ __launch_bounds__(256) void hop_kernel(
    const unsigned short* __restrict__ xin, unsigned short* __restrict__ xout,
    const float* __restrict__ dinv, const unsigned int* __restrict__ bucket,
    const int* __restrict__ cnt) {
    int t = threadIdx.x;
    int lane = t & 63;
    int wid  = t >> 6;
    int q = lane & 31;                       // lane within half-wave
    int h = lane >> 5;                       // which half
    int i = blockIdx.x * 8 + wid * 2 + h;    // node for this half-wave

    int c = min(cnt[i], CAP);
    float di = dinv[i];
    int r0 = i, r1 = i;
    float n0 = 0.0f, n1 = 0.0f;
    if (q < c) {
        unsigned int ent = bucket[i * CAP + q];
        r0 = (int)(ent & 0xFFFFu);
        float w = __half2float(__ushort_as_half((unsigned short)(ent >> 16)));
        n0 = di * dinv[r0] * w;
    }
    if (q + 32 < c) {
        unsigned int ent = bucket[i * CAP + q + 32];
        r1 = (int)(ent & 0xFFFFu);
        float w = __half2float(__ushort_as_half((unsigned short)(ent >> 16)));
        n1 = di * dinv[r1] * w;
    }
    int cmax = max(c, __shfl_xor(c, 32, 64));   // wave-uniform loop bound

    uint2 sv = *(const uint2*)(xin + (size_t)i * F + q * 4);
    float2 slo = __half22float2(*(const __half2*)&sv.x);
    float2 shi = __half22float2(*(const __half2*)&sv.y);
    float dii = di * di;
    float4 acc = make_float4(dii * slo.x, dii * slo.y, dii * shi.x, dii * shi.y);

    int kend1 = cmax < 32 ? cmax : 32;
    int k = 0;
    for (; k + 8 <= kend1; k += 8) {
        int rr[8]; float nn[8]; uint2 v[8];
        #pragma unroll
        for (int j = 0; j < 8; ++j) {
            rr[j] = __shfl(r0, k + j, 32);
            nn[j] = __shfl(n0, k + j, 32);
        }
        #pragma unroll
        for (int j = 0; j < 8; ++j)
            v[j] = *(const uint2*)(xin + (size_t)rr[j] * F + q * 4);
        #pragma unroll
        for (int j = 0; j < 8; ++j) {
            float2 lo = __half22float2(*(const __half2*)&v[j].x);
            float2 hi = __half22float2(*(const __half2*)&v[j].y);
            acc.x += nn[j] * lo.x; acc.y += nn[j] * lo.y;
            acc.z += nn[j] * hi.x; acc.w += nn[j] * hi.y;
        }
    }
    for (; k < kend1; ++k) {
        int   rk = __shfl(r0, k, 32);
        float nk = __shfl(n0, k, 32);
        uint2 v  = *(const uint2*)(xin + (size_t)rk * F + q * 4);
        float2 lo = __half22float2(*(const __half2*)&v.x);
        float2 hi = __half22float2(*(const __half2*)&v.y);
        acc.x += nk * lo.x; acc.y += nk * lo.y;
        acc.z += nk * hi.x; acc.w += nk * hi.y;
    }
    for (; k + 8 <= cmax; k += 8) {
        int rr[8]; float nn[8]; uint2 v[8];
        #pragma unroll
        for (int j = 0; j < 8; ++j) {
            rr[j] = __shfl(r1, k - 32 + j, 32);
            nn[j] = __shfl(n1, k - 32 + j, 32);
        }
        #pragma unroll
        for (int j = 0; j < 8; ++j)
            v[j] = *(const uint2*)(xin + (size_t)rr[j] * F + q * 4);
        #pragma unroll
        for (int j = 0; j < 8; ++j) {
            float2 lo = __half22float2(*(const __half2*)&v[j].x);
            float2 hi = __half22float2(*(const __half2*)&v[j].y);
            acc.x += nn[j] * lo.x; acc.y += nn[j] * lo.y;
            acc.z += nn[j] * hi.x; acc.w += nn[j] * hi.y;
        }
    }
    for (; k < cmax; ++k) {
        int   rk = __shfl(r1, k - 32, 32);
        float nk = __shfl(n1, k - 32, 32);
        uint2 v  = *(const uint2*)(xin + (size_t)rk * F + q * 4);
        float2 lo = __half22float2(*(const __half2*)&v.x);
        float2 hi = __half22float2(*(const __half2*)&v.y);
        acc.x += nk * lo.x; acc.y += nk * lo.y;
        acc.z += nk * hi.x; acc.w += nk * hi.y;
    }

    uint2 o;
    *(__half2*)&o.x = __float22half2_rn(make_float2(acc.x, acc.y));
    *(__half2*)&o.y = __float22half2_rn(make_float2(acc.z, acc.w));
    *(uint2*)&xout[(size_t)i * F + q * 4] = o;
}

// ---------------------------------------------------------------------------
// K4: hop 2 fused with linear. 512 threads = 8 waves = 16 nodes/block.
// Gather loop identical to hop_kernel (i = block*16 + wid*2 + h); result
// staged as fp16 into LDS tile [16][TPAD], then wave `wid` computes out
// features [wid*16, wid*16+16) via 4 chained mfma_f32_16x16x32_f16 and
// writes `out` (+bias) directly. A[m=lane&15][k=quad*8+j] read from tile;
// B from Wh; D col=lane&15 (=f-in-tile), row=quad*4+reg (=node).
__global__ __launch_bounds__(512) void hop_linear_kernel(
    const unsigned short* __restrict__ xin, const unsigned short* __restrict__ Wh,
    const float* __restrict__ bias, float* __restrict__ out,
    const float* __restrict__ dinv, const unsigned int* __restrict__ bucket,
    const int* __restrict__ cnt) {
    __shared__ unsigned short tile[16][TPAD];
    int t = threadIdx.x;
    int lane = t & 63;
    int wid  = t >> 6;                        // 0..7
    int q = lane & 31;                        // lane within half-wave
    int h = lane >> 5;                        // which half
    int row = wid * 2 + h;                    // node-in-tile 0..15
    int i = blockIdx.x * 16 + row;            // node for this half-wave

    int c = min(cnt[i], CAP);
    float di = dinv[i];
    int r0 = i, r1 = i;
    float n0 = 0.0f, n1 = 0.0f;
    if (q < c) {
        unsigned int ent = bucket[i * CAP + q];
        r0 = (int)(ent & 0xFFFFu);
        float w = __half2float(__ushort_as_half((unsigned short)(ent >> 16)));
        n0 = di * dinv[r0] * w;
    }
    if (q + 32 < c) {
        unsigned int ent = bucket[i * CAP + q + 32];
        r1 = (int)(ent & 0xFFFFu);
        float w = __half2float(__ushort_as_half((unsigned short)(ent >> 16)));
        n1 = di * dinv[r1] * w;
    }
    int cmax = max(c, __shfl_xor(c, 32, 64));   // wave-uniform loop bound

    uint2 sv = *(const uint2*)(xin + (size_t)i * F + q * 4);
    float2 slo = __half22float2(*(const __half2*)&sv.x);
    float2 shi = __half22float2(*(const __half2*)&sv.y);
    float dii = di * di;
    float4 acc = make_float4(dii * slo.x, dii * slo.y, dii * shi.x, dii * shi.y);

    int kend1 = cmax < 32 ? cmax : 32;
    int k = 0;
    for (; k + 8 <= kend1; k += 8) {
        int rr[8]; float nn[8]; uint2 v[8];
        #pragma unroll
        for (int j = 0; j < 8; ++j) {
            rr[j] = __shfl(r0, k + j, 32);
            nn[j] = __shfl(n0, k + j, 32);
        }
        #pragma unroll
        for (int j = 0; j < 8; ++j)
            v[j] = *(const uint2*)(xin + (size_t)rr[j] * F + q * 4);
        #pragma unroll
        for (int j = 0; j < 8; ++j) {
            float2 lo = __half22float2(*(const __half2*)&v[j].x);
            float2 hi = __half22float2(*(const __half2*)&v[j].y);
            acc.x += nn[j] * lo.x; acc.y += nn[j] * lo.y;
            acc.z += nn[j] * hi.x; acc.w += nn[j] * hi.y;
        }
    }
    for (; k < kend1; ++k) {
        int   rk = __shfl(r0, k, 32);
        float nk = __shfl(n0, k, 32);
        uint2 v  = *(const uint2*)(xin + (size_t)rk * F + q * 4);
        float2 lo = __half22float2(*(const __half2*)&v.x);
        float2 hi = __half22float2(*(const __half2*)&v.y);
        acc.x += nk * lo.x; acc.y += nk * lo.y;
        acc.z += nk * hi.x; acc.w += nk * hi.y;
    }
    for (; k + 8 <= cmax; k += 8) {
        int rr[8]; float nn[8]; uint2 v[8];
        #pragma unroll
        for (int j = 0; j < 8; ++j) {
            rr[j] = __shfl(r1, k - 32 + j, 32);
            nn[j] = __shfl(n1, k - 32 + j, 32);
        }
        #pragma unroll
        for (int j = 0; j < 8; ++j)
            v[j] = *(const uint2*)(xin + (size_t)rr[j] * F + q * 4);
        #pragma unroll
        for (int j = 0; j < 8; ++j) {
            float2 lo = __half22float2(*(const __half2*)&v[j].x);
            float2 hi = __half22float2(*(const __half2*)&v[j].y);
            acc.x += nn[j] * lo.x; acc.y += nn[j] * lo.y;
            acc.z += nn[j] * hi.x; acc.w += nn[j] * hi.y;
        }
    }
    for (; k < cmax; ++k) {
        int   rk = __shfl(r1, k - 32, 32);
        float nk = __shfl(n1, k - 32, 32);
        uint2 v  = *(const uint2*)(xin + (size_t)rk * F + q * 4);
        float2 lo = __half22float2(*(const __half2*)&v.x);
        float2 hi = __half22float2(*(const __half2*)&v.y);
        acc.x += nk * lo.x; acc.y += nk * lo.y;
        acc.z += nk * hi.x; acc.w += nk * hi.y;
    }

    // stage fp16 row into LDS (same rounding as the old x2h path)
    uint2 o;
    *(__half2*)&o.x = __float22half2_rn(make_float2(acc.x, acc.y));
    *(__half2*)&o.y = __float22half2_rn(make_float2(acc.z, acc.w));
    *(uint2*)&tile[row][q * 4] = o;
    __syncthreads();

    // MFMA epilogue: wave wid -> out-features [wid*16, wid*16+16)
    int m    = lane & 15;
    int quad = lane >> 4;
    f32x4 acc2 = (f32x4){0.f, 0.f, 0.f, 0.f};
    #pragma unroll
    for (int ks = 0; ks < 4; ++ks) {
        f16x8 a = *(const f16x8*)&tile[m][ks * 32 + quad * 8];
        f16x8 b = *(const f16x8*)(Wh + (size_t)(wid * 16 + m) * F + ks * 32 + quad * 8);
        acc2 = __builtin_amdgcn_mfma_f32_16x16x32_f16(a, b, acc2, 0, 0, 0);
    }
    int n0b = blockIdx.x * 16;
    int f = wid * 16 + m;
    float bv = bias[f];
    #pragma unroll
    for (int reg = 0; reg < 4; ++reg) {
        int n = n0b + quad * 4 + reg;
        out[(size_t)n * F + f] = acc2[reg] + bv;
    }
}

// ---------------------------------------------------------------------------
extern "C" void kernel_launch(void* const* d_in, const int* in_sizes, int n_in,
                              void* d_out, int out_size, void* d_ws, size_t ws_size,
                              hipStream_t stream) {
    const float* x    = (const float*)d_in[0];
    const int*   ei   = (const int*)d_in[1];     // int32 per harness contract
    const float* ew   = (const float*)d_in[2];
    const float* W    = (const float*)d_in[3];
    const float* bias = (const float*)d_in[4];
    float* out = (float*)d_out;

    const int N = in_sizes[0] / F;   // 40000
    const int E = in_sizes[2];       // 640000

    const int nbin = (N + 255) >> 8;          // 157 bins of 256 nodes
    const int nb1  = (E + EPB - 1) / EPB;     // 157 build blocks

    // workspace layout (256B aligned); nothing needs zeroing
    char* ws = (char*)d_ws;
    size_t off = 0;
    auto take = [&](size_t bytes) {
        size_t r = off;
        off = (off + bytes + 255) & ~(size_t)255;
        return r;
    };
    size_t o_cnt1   = take((size_t)nb1 * nbin * 4);          // [blk][bin] counts
    size_t o_coarse = take((size_t)nbin * nb1 * CAP * 8);    // uint2 segments, 12.6MB
    size_t o_cnt    = take((size_t)N * 4);                   // int per node
    size_t o_dinv   = take((size_t)N * 4);                   // float
    size_t o_bucket = take((size_t)N * CAP * 4);             // packed uint entries
    size_t o_xh     = take((size_t)N * F * 2);               // half [N][128]
    size_t o_x1h    = take((size_t)N * F * 2);               // half [N][128]
    size_t o_wh     = take((size_t)F * F * 2);               // half [128][128]
    (void)ws_size;

    int*            cnt1   = (int*)(ws + o_cnt1);
    uint2*          coarse = (uint2*)(ws + o_coarse);
    int*            cnt    = (int*)(ws + o_cnt);
    float*          dinv   = (float*)(ws + o_dinv);
    unsigned int*   bucket = (unsigned int*)(ws + o_bucket);
    __half2*        xh2    = (__half2*)(ws + o_xh);
    unsigned short* xh     = (unsigned short*)(ws + o_xh);
    unsigned short* x1h    = (unsigned short*)(ws + o_x1h);
    __half2*        wh2    = (__half2*)(ws + o_wh);
    unsigned short* wh     = (unsigned short*)(ws + o_wh);

    int npairs = N * 64;
    int cvtBlocks = (npairs + 255) / 256;      // 10000
    int wBlocks   = (F * F / 2 + 255) / 256;   // 32
    prep_kernel<<<nb1 + cvtBlocks + wBlocks, 256, 0, stream>>>(
        (const float2*)x, xh2, npairs, ei, ew, coarse, cnt1, E, nbin, nb1,
        (const float2*)W, wh2, nb1, cvtBlocks);
    finalize_kernel<<<nbin, 1024, 0, stream>>>(coarse, cnt1, bucket, cnt, dinv,
                                               N, nbin, nb1);
    hop_kernel<<<N / 8, 256, 0, stream>>>(xh, x1h, dinv, bucket, cnt);
    hop_linear_kernel<<<N / 16, 512, 0, stream>>>(x1h, wh, bias, out,
                                                  dinv, bucket, cnt);
}